// Round 14
// baseline (592.218 us; speedup 1.0000x reference)
//
#include <hip/hip_runtime.h>
#include <hip/hip_bf16.h>

typedef __hip_bfloat16 bf16;
typedef __bf16 bf16x8 __attribute__((ext_vector_type(8)));
typedef float f32x4 __attribute__((ext_vector_type(4)));

#define SEQ 256
#define NB  64
#define NV  300
#define NH  256
#define G3  768
#define D2  512
#define LOG2E  1.44269504f
#define LOG2E2 2.88539008f

__device__ __forceinline__ ushort f2bs(float f){ __bf16 t = (__bf16)f; return *(ushort*)&t; }
__device__ __forceinline__ float u2f(uint u){ return __uint_as_float(u); }

__device__ __forceinline__ float ex2(float x){
#if __has_builtin(__builtin_amdgcn_exp2f)
  return __builtin_amdgcn_exp2f(x);
#else
  return __exp2f(x);
#endif
}
__device__ __forceinline__ float rcp_(float x){
#if __has_builtin(__builtin_amdgcn_rcpf)
  return __builtin_amdgcn_rcpf(x);
#else
  return 1.0f/x;
#endif
}

// fp32 64x64 tile helper (used by fc1)
__device__ __forceinline__ void mm16(const float (*As)[68], const float (*Bs)[68],
                                     float acc[4][4], int ty, int tx){
  #pragma unroll
  for (int kk=0;kk<16;kk++){
    const float4 a4 = *(const float4*)&As[kk][ty*4];
    const float4 b4 = *(const float4*)&Bs[kk][tx*4];
    const float ai[4] = {a4.x,a4.y,a4.z,a4.w};
    const float bj[4] = {b4.x,b4.y,b4.z,b4.w};
    #pragma unroll
    for (int i=0;i<4;i++)
      #pragma unroll
      for (int j=0;j<4;j++)
        acc[i][j] = fmaf(ai[i], bj[j], acc[i][j]);
  }
}

// === prep: gathered embedding -> bf16, K padded 300->320 ===
__global__ __launch_bounds__(320) void k_emb(const int* __restrict__ x,
                                             const float* __restrict__ embed,
                                             ushort* __restrict__ E){
  const int t = threadIdx.x;
  const int rsub = t / 80, c4 = t - rsub*80;
  const int row = blockIdx.x*4 + rsub;           // 32768 rows = s*16384 + b*256 + n
  const int s = row >> 14, b = (row >> 8) & 63, n = row & 255;
  const int token = x[(b*2 + s)*SEQ + n];
  const int k = c4*4;
  float4 v = make_float4(0,0,0,0);
  if (k < NV) v = *(const float4*)(embed + (size_t)token*NV + k);
  ushort4 o;
  o.x = f2bs(v.x); o.y = f2bs(v.y); o.z = f2bs(v.z); o.w = f2bs(v.w);
  *(ushort4*)(E + (size_t)row*320 + k) = o;
}

// === prep: W_ih (f then b) -> bf16 [1536][320] ===
__global__ __launch_bounds__(320) void k_wih(const float* __restrict__ Wf,
                                             const float* __restrict__ Wb,
                                             ushort* __restrict__ W16){
  const int t = threadIdx.x;
  const int rsub = t / 80, c4 = t - rsub*80;
  const int g = blockIdx.x*4 + rsub;             // 0..1535
  const int dir = g >= G3;
  const int gw = g - dir*G3;
  const float* __restrict__ W = dir ? Wb : Wf;
  const int k = c4*4;
  float4 v = make_float4(0,0,0,0);
  if (k < NV) v = *(const float4*)(W + (size_t)gw*NV + k);
  ushort4 o;
  o.x = f2bs(v.x); o.y = f2bs(v.y); o.z = f2bs(v.z); o.w = f2bs(v.w);
  *(ushort4*)(W16 + (size_t)g*320 + k) = o;
}

// === prep: W_hh -> bf16 MFMA B-frag layout for 16-wave k_gru, log2e-scaled ===
__global__ __launch_bounds__(256) void k_wpk(const float* __restrict__ Wf,
                                             const float* __restrict__ Wb,
                                             ushort* __restrict__ wpk){
  const int idx = blockIdx.x*256 + threadIdx.x;   // 49152
  const int l   = idx & 63;
  const int kf  = (idx >> 6) & 7;
  const int r2  = idx >> 9;                        // (dir*16+w)*3 + tau
  const int tau = r2 % 3;
  const int r3  = r2 / 3;
  const int w   = r3 & 15;
  const int dir = r3 >> 4;
  const int g   = tau*256 + w*16 + (l & 15);
  const int kb  = kf*32 + (l >> 4)*8;
  const float sc = (tau < 2) ? LOG2E : LOG2E2;
  const float* __restrict__ W = dir ? Wb : Wf;
  #pragma unroll
  for (int e=0;e<8;e++)
    wpk[(size_t)idx*8 + e] = f2bs(W[(size_t)g*NH + kb + e] * sc);
}

// === xg GEMM (MFMA): 128x256 tiles; E re-read halved; tau WG-constant ===
// xgq layout: [blk = chain*16 + slice16][n][r4(4)][tau(3)][u(256)] bf16
__global__ __launch_bounds__(256) void k_xgm(const ushort* __restrict__ E,
    const ushort* __restrict__ W16,
    const float* __restrict__ bihf, const float* __restrict__ bihb,
    const float* __restrict__ bhhf, const float* __restrict__ bhhb,
    char* __restrict__ xgq)
{
  __shared__ __align__(16) char SM[34816];   // loop: As[0,10240)+Bs[10240,30720); epi: Cs[128][272B]
  char* As = SM;
  char* Bs = SM + 10240;
  const int tid = threadIdx.x, w = tid >> 6, l = tid & 63, l15 = l & 15, lg = l >> 4;
  const int r0 = blockIdx.x * 128;
  const int c0 = blockIdx.y * 256;           // 0,256,512 (dir0) / 768,1024,1280 (dir1)
  const int dir = (c0 >= G3);
  const int cw0 = c0 - dir*G3;               // 0,256,512
  const int tau = cw0 >> 8;                  // WG-constant
  const float sc2 = (tau < 2) ? LOG2E : LOG2E2;
  const float* __restrict__ bih = dir ? bihb : bihf;
  const float* __restrict__ bhh = dir ? bhhb : bhhf;

  const int srow = tid >> 1, sca = (tid & 1)*32;
  f32x4 acc[2][16] = {};

  for (int ks = 0; ks < 10; ks++){
    const uint4 a0 = *(const uint4*)((const char*)E + (size_t)(r0+srow)*640 + ks*64 + sca);
    const uint4 a1 = *(const uint4*)((const char*)E + (size_t)(r0+srow)*640 + ks*64 + sca + 16);
    const uint4 b0 = *(const uint4*)((const char*)W16 + (size_t)(c0+tid)*640 + ks*64);
    const uint4 b1 = *(const uint4*)((const char*)W16 + (size_t)(c0+tid)*640 + ks*64 + 16);
    const uint4 b2 = *(const uint4*)((const char*)W16 + (size_t)(c0+tid)*640 + ks*64 + 32);
    const uint4 b3 = *(const uint4*)((const char*)W16 + (size_t)(c0+tid)*640 + ks*64 + 48);
    __syncthreads();
    *(uint4*)&As[srow*80 + sca] = a0;
    *(uint4*)&As[srow*80 + sca + 16] = a1;
    *(uint4*)&Bs[tid*80 +  0] = b0;
    *(uint4*)&Bs[tid*80 + 16] = b1;
    *(uint4*)&Bs[tid*80 + 32] = b2;
    *(uint4*)&Bs[tid*80 + 48] = b3;
    __syncthreads();
    bf16x8 am[2];
    #pragma unroll
    for (int mm=0;mm<2;mm++) am[mm] = *(const bf16x8*)&As[(w*32 + mm*16 + l15)*80 + lg*16];
    #pragma unroll
    for (int h=0; h<2; h++){
      bf16x8 bn[8];
      #pragma unroll
      for (int q=0;q<8;q++) bn[q] = *(const bf16x8*)&Bs[((h*8+q)*16 + l15)*80 + lg*16];
      #pragma unroll
      for (int mm=0;mm<2;mm++)
        #pragma unroll
        for (int q=0;q<8;q++)
          acc[mm][h*8+q] = __builtin_amdgcn_mfma_f32_16x16x32_bf16(am[mm], bn[q], acc[mm][h*8+q], 0,0,0);
    }
  }

  // epilogue: two u-halves; Cs [128 rows][136 u16]; coalesced 256B runs out
  ushort* Cs = (ushort*)SM;
  #pragma unroll
  for (int p=0; p<2; p++){
    __syncthreads();
    #pragma unroll
    for (int q=0;q<8;q++){
      const int nt = p*8 + q;
      const int cwb = cw0 + nt*16;
      const float bias = bih[cwb + l15] + ((tau < 2) ? bhh[cwb + l15] : 0.0f);
      #pragma unroll
      for (int mm=0;mm<2;mm++)
        #pragma unroll
        for (int j=0;j<4;j++){
          const int row = w*32 + mm*16 + lg*4 + j;
          Cs[row*136 + q*16 + l15] = f2bs((acc[mm][nt][j] + bias) * sc2);
        }
    }
    __syncthreads();
    #pragma unroll
    for (int i=0;i<8;i++){
      const int idx = i*256 + tid;     // 0..2047
      const int row = idx >> 4, c16 = idx & 15;
      const int R = r0 + row;
      const int s_ = R >> 14, b_ = (R >> 8) & 63, n_ = R & 255;
      const int blk = (s_*2 + dir)*16 + (b_ >> 2);
      const uint4 v = *(const uint4*)&Cs[row*136 + c16*8];
      *(uint4*)(xgq + ((size_t)blk*256 + n_)*6144 + ((b_&3)*3 + tau)*512 + p*256 + c16*16) = v;
    }
  }
}

// === GRU recurrence: 64 WGs x 1024 threads (16 waves, 4/SIMD) — round-8 body ===
#define HSTR 544
__global__ __launch_bounds__(1024, 4) void k_gru(const char* __restrict__ xgq,
      const ushort* __restrict__ wpk,
      const float* __restrict__ bhhf, const float* __restrict__ bhhb,
      ushort* __restrict__ o2b)
{
  __shared__ __align__(16) char SMEM[2*16*HSTR];   // 17408 B
  const int tid = threadIdx.x, w = tid >> 6, l = tid & 63, l15 = l & 15, lg = l >> 4;
  const int wgid = blockIdx.x;
  const int chain = wgid >> 4, sl = wgid & 15;
  const int s = chain >> 1, dir = chain & 1;
  const int sb64 = s*64 + sl*4;
  const float* __restrict__ bhh = dir ? bhhb : bhhf;
  const char* wbg = (const char*)wpk + (size_t)(dir*16 + w) * 24576;

  bf16x8 Wr[3][8];
  #pragma unroll
  for (int tau=0; tau<3; tau++)
    #pragma unroll
    for (int kf=0; kf<8; kf++)
      Wr[tau][kf] = *(const bf16x8*)(wbg + (size_t)((tau*8 + kf)*64 + l)*16);

  const float bn = bhh[512 + w*16 + l15] * LOG2E2;

  for (int k = tid; k < 4352; k += 1024) ((float*)SMEM)[k] = 0.0f;

  const int n0 = dir ? 255 : 0;
  const int qstep = dir ? -6144 : 6144;
  const int ostep = dir ? -1024 : 1024;
  const char* qb = xgq + ((size_t)wgid*256 + n0)*6144 + lg*1536 + (w*16 + l15)*2;
  char* op = (char*)o2b + ((size_t)(sb64 + lg)*256 + n0)*1024 + dir*512 + (w*16 + l15)*2;

  const int aoff = l15*HSTR + lg*16;
  const int hwoff = lg*4*HSTR + (w*16 + l15)*2;
  float hpv = 0.0f;

  __syncthreads();

  #pragma unroll 1
  for (int t=0; t<SEQ; t++){
    const int cur = t & 1;
    const int hcur = cur*8704, hnxt = (cur^1)*8704;

    const ushort q0 = *(const ushort*)(qb);
    const ushort q1 = *(const ushort*)(qb + 512);
    const ushort q2 = *(const ushort*)(qb + 1024);
    qb += qstep;

    f32x4 C[3] = {};
    #pragma unroll
    for (int kf=0; kf<8; kf++){
      const bf16x8 a = *(const bf16x8*)&SMEM[hcur + aoff + kf*64];
      C[0] = __builtin_amdgcn_mfma_f32_16x16x32_bf16(a, Wr[0][kf], C[0], 0, 0, 0);
      C[1] = __builtin_amdgcn_mfma_f32_16x16x32_bf16(a, Wr[1][kf], C[1], 0, 0, 0);
      C[2] = __builtin_amdgcn_mfma_f32_16x16x32_bf16(a, Wr[2][kf], C[2], 0, 0, 0);
    }

    const float xr = u2f((uint)q0 << 16);
    const float xz = u2f((uint)q1 << 16);
    const float xn = u2f((uint)q2 << 16);
    const float r  = rcp_(1.0f + ex2(-(xr + C[0][0])));
    const float z  = rcp_(1.0f + ex2(-(xz + C[1][0])));
    const float e2 = ex2(xn + r*(C[2][0] + bn));
    const float nn = (e2 - 1.0f) * rcp_(e2 + 1.0f);
    const float h  = nn + z*(hpv - nn);
    hpv = h;
    const ushort hs = f2bs(h);
    *(ushort*)&SMEM[hnxt + hwoff] = hs;
    *(ushort*)op = hs;
    op += ostep;
    __syncthreads();
  }
}

// === transpose o2b -> o2t (bf16), per sb 64x64 tiles ===
__global__ __launch_bounds__(256) void k_tr(const ushort* __restrict__ o2b,
                                            ushort* __restrict__ o2t){
  __shared__ __align__(16) char Ts[64*144];
  const int t = threadIdx.x;
  const int sb = blockIdx.z;
  const int n0 = blockIdx.x*64, d0 = blockIdx.y*64;
  const char* src = (const char*)o2b + (size_t)sb*262144;
  char* dst = (char*)o2t + (size_t)sb*262144;
  const int r = t >> 3, ch = t & 7;
  #pragma unroll
  for (int p=0;p<2;p++){
    const int row = r + p*32;
    const uint4 v = *(const uint4*)(src + (size_t)(n0+row)*1024 + d0*2 + ch*16);
    *(uint4*)&Ts[row*144 + ch*16] = v;
  }
  __syncthreads();
  #pragma unroll
  for (int p=0;p<2;p++){
    const int d = r + p*32;
    uint o[4];
    #pragma unroll
    for (int i=0;i<4;i++){
      const uint lo = *(const ushort*)&Ts[(ch*8 + 2*i)*144 + d*2];
      const uint hi = *(const ushort*)&Ts[(ch*8 + 2*i + 1)*144 + d*2];
      o[i] = lo | (hi << 16);
    }
    *(uint4*)(dst + (size_t)(d0+d)*512 + n0*2 + ch*16) = *(uint4*)o;
  }
}

// === scores (MFMA): o2b @ o2b^T - dist ===
__global__ __launch_bounds__(256) void k_scores(const ushort* __restrict__ o2b,
                                                float* __restrict__ sc){
  __shared__ __align__(16) char As[64*144];
  __shared__ __align__(16) char Bs[64*144];
  const int tid = threadIdx.x, w = tid >> 6, l = tid & 63, l15 = l & 15, lg = l >> 4;
  const int sb = blockIdx.z;
  const int n0 = blockIdx.x*64, m0 = blockIdx.y*64;
  const char* ob = (const char*)o2b + (size_t)sb*262144;
  const int srow = tid >> 2, scf = (tid & 3)*16;
  f32x4 acc[4] = {};
  for (int it=0; it<8; it++){
    const int k0 = it*64;
    const uint4 a0 = *(const uint4*)(ob + (size_t)(n0+srow)*1024 + k0*2 + scf);
    const uint4 a1 = *(const uint4*)(ob + (size_t)(n0+srow)*1024 + k0*2 + scf + 64);
    const uint4 b0 = *(const uint4*)(ob + (size_t)(m0+srow)*1024 + k0*2 + scf);
    const uint4 b1 = *(const uint4*)(ob + (size_t)(m0+srow)*1024 + k0*2 + scf + 64);
    __syncthreads();
    *(uint4*)&As[srow*144 + scf] = a0;
    *(uint4*)&As[srow*144 + scf + 64] = a1;
    *(uint4*)&Bs[srow*144 + scf] = b0;
    *(uint4*)&Bs[srow*144 + scf + 64] = b1;
    __syncthreads();
    #pragma unroll
    for (int ks=0; ks<2; ks++){
      const bf16x8 a = *(const bf16x8*)&As[(w*16 + l15)*144 + ks*64 + lg*16];
      #pragma unroll
      for (int nt=0; nt<4; nt++){
        const bf16x8 b = *(const bf16x8*)&Bs[(nt*16 + l15)*144 + ks*64 + lg*16];
        acc[nt] = __builtin_amdgcn_mfma_f32_16x16x32_bf16(a, b, acc[nt], 0, 0, 0);
      }
    }
  }
  #pragma unroll
  for (int nt=0; nt<4; nt++)
    #pragma unroll
    for (int j=0; j<4; j++){
      const int n = n0 + w*16 + lg*4 + j;
      const int m = m0 + nt*16 + l15;
      const float d = (float)(n - m);
      sc[((size_t)sb*SEQ + n)*SEQ + m] = acc[nt][j] - d*d*(1.0f/0.95f);
    }
}

// === softmax rows -> P bf16 ===
__global__ __launch_bounds__(256) void k_softmax(const float* __restrict__ sc,
                                                 ushort* __restrict__ P){
  const int row = blockIdx.x*4 + (threadIdx.x >> 6);
  const int lane = threadIdx.x & 63;
  const float4 v = *(const float4*)(sc + (size_t)row*SEQ + lane*4);
  float m = fmaxf(fmaxf(v.x,v.y), fmaxf(v.z,v.w));
  #pragma unroll
  for (int off=32; off; off>>=1) m = fmaxf(m, __shfl_xor(m, off));
  float4 e;
  e.x = __expf(v.x-m); e.y = __expf(v.y-m); e.z = __expf(v.z-m); e.w = __expf(v.w-m);
  float ssum = e.x+e.y+e.z+e.w;
  #pragma unroll
  for (int off=32; off; off>>=1) ssum += __shfl_xor(ssum, off);
  const float inv = 1.0f/ssum;
  uint2 o;
  o.x = (uint)f2bs(e.x*inv) | ((uint)f2bs(e.y*inv) << 16);
  o.y = (uint)f2bs(e.z*inv) | ((uint)f2bs(e.w*inv) << 16);
  *(uint2*)((char*)P + (size_t)row*512 + lane*8) = o;
}

// === o5 (MFMA) + fused pool partials: P @ o2 -> per-WG sum/max over its 64 n ===
// psum/pmax: [sb][4 n-tiles][512 d] f32
__global__ __launch_bounds__(256) void k_o5(const ushort* __restrict__ P,
                                            const ushort* __restrict__ o2t,
                                            float* __restrict__ psum,
                                            float* __restrict__ pmax){
  __shared__ __align__(16) char As[64*144];
  __shared__ __align__(16) char Bs[64*144];
  const int tid = threadIdx.x, w = tid >> 6, l = tid & 63, l15 = l & 15, lg = l >> 4;
  const int sb = blockIdx.z;
  const int n0 = blockIdx.x*64, d0 = blockIdx.y*64;
  const char* pa = (const char*)P + (size_t)sb*131072;
  const char* pb = (const char*)o2t + (size_t)sb*262144;
  const int srow = tid >> 2, scf = (tid & 3)*16;
  f32x4 acc[4] = {};
  for (int it=0; it<4; it++){
    const int k0 = it*64;
    const uint4 a0 = *(const uint4*)(pa + (size_t)(n0+srow)*512 + k0*2 + scf);
    const uint4 a1 = *(const uint4*)(pa + (size_t)(n0+srow)*512 + k0*2 + scf + 64);
    const uint4 b0 = *(const uint4*)(pb + (size_t)(d0+srow)*512 + k0*2 + scf);
    const uint4 b1 = *(const uint4*)(pb + (size_t)(d0+srow)*512 + k0*2 + scf + 64);
    __syncthreads();
    *(uint4*)&As[srow*144 + scf] = a0;
    *(uint4*)&As[srow*144 + scf + 64] = a1;
    *(uint4*)&Bs[srow*144 + scf] = b0;
    *(uint4*)&Bs[srow*144 + scf + 64] = b1;
    __syncthreads();
    #pragma unroll
    for (int ks=0; ks<2; ks++){
      const bf16x8 a = *(const bf16x8*)&As[(w*16 + l15)*144 + ks*64 + lg*16];
      #pragma unroll
      for (int nt=0; nt<4; nt++){
        const bf16x8 b = *(const bf16x8*)&Bs[(nt*16 + l15)*144 + ks*64 + lg*16];
        acc[nt] = __builtin_amdgcn_mfma_f32_16x16x32_bf16(a, b, acc[nt], 0, 0, 0);
      }
    }
  }
  // in-WG pool over the 64 n rows this WG owns (fp32)
  __syncthreads();
  float* Ss = (float*)As;   // [16 wlg][4 nt][16 l15]
  float* Ms = (float*)Bs;
  const int wlg = w*4 + lg;
  #pragma unroll
  for (int nt=0; nt<4; nt++){
    const float s4 = acc[nt][0] + acc[nt][1] + acc[nt][2] + acc[nt][3];
    const float m4 = fmaxf(fmaxf(acc[nt][0], acc[nt][1]), fmaxf(acc[nt][2], acc[nt][3]));
    Ss[wlg*64 + nt*16 + l15] = s4;
    Ms[wlg*64 + nt*16 + l15] = m4;
  }
  __syncthreads();
  if (tid < 64){
    float s = 0.0f, m = -1e30f;
    #pragma unroll
    for (int k=0; k<16; k++){
      s += Ss[k*64 + tid];
      m = fmaxf(m, Ms[k*64 + tid]);
    }
    psum[((size_t)sb*4 + blockIdx.x)*512 + d0 + tid] = s;
    pmax[((size_t)sb*4 + blockIdx.x)*512 + d0 + tid] = m;
  }
}

// === combine pool partials -> feats ===
__global__ __launch_bounds__(256) void k_poolc(const float* __restrict__ psum,
                                               const float* __restrict__ pmax,
                                               float* __restrict__ feats){
  const int idx = blockIdx.x*256 + threadIdx.x;  // 128*512
  const int sb = idx >> 9, d = idx & 511;
  float s = 0.0f, m = -1e30f;
  #pragma unroll
  for (int nb=0; nb<4; nb++){
    s += psum[((size_t)sb*4 + nb)*512 + d];
    m = fmaxf(m, pmax[((size_t)sb*4 + nb)*512 + d]);
  }
  feats[(size_t)sb*1024 + d] = s*(1.0f/256.0f);
  feats[(size_t)sb*1024 + 512 + d] = m;
}

__global__ __launch_bounds__(256) void k_z(const float* __restrict__ feats,
                                           float* __restrict__ Z){
  const int idx = blockIdx.x*256 + threadIdx.x;
  const int b = idx >> 11, k = idx & 2047;
  const int j = (k < 1024) ? k : (k - 1024);
  const float fa = feats[(size_t)b*1024 + j];
  const float fb = feats[(size_t)(64 + b)*1024 + j];
  Z[idx] = (k < 1024) ? fabsf(fa - fb) : fa*fb;
}

__global__ __launch_bounds__(256) void k_fc1(const float* __restrict__ Z,
                                             const float* __restrict__ w,
                                             const float* __restrict__ bias,
                                             float* __restrict__ h1){
  __shared__ float As[16][68];
  __shared__ float Bs[16][68];
  const int tid = threadIdx.x;
  const int c0 = blockIdx.x*64;
  const int lr = tid >> 2, lk = (tid & 3)*4;
  const int ty = tid >> 4, tx = tid & 15;
  float acc[4][4] = {};
  for (int k0=0;k0<2048;k0+=16){
    const float4 a = *(const float4*)(Z + (size_t)lr*2048 + k0 + lk);
    const float4 b = *(const float4*)(w + (size_t)(c0+lr)*2048 + k0 + lk);
    __syncthreads();
    As[lk+0][lr]=a.x; As[lk+1][lr]=a.y; As[lk+2][lr]=a.z; As[lk+3][lr]=a.w;
    Bs[lk+0][lr]=b.x; Bs[lk+1][lr]=b.y; Bs[lk+2][lr]=b.z; Bs[lk+3][lr]=b.w;
    __syncthreads();
    mm16(As, Bs, acc, ty, tx);
  }
  #pragma unroll
  for (int i=0;i<4;i++)
    #pragma unroll
    for (int j=0;j<4;j++)
      h1[(size_t)(ty*4+i)*512 + c0+tx*4+j] = fmaxf(acc[i][j] + bias[c0+tx*4+j], 0.0f);
}

__global__ __launch_bounds__(256) void k_fc2(const float* __restrict__ h1,
                                             const float* __restrict__ w2,
                                             const float* __restrict__ b2,
                                             float* __restrict__ out){
  __shared__ float red[256];
  const int b = blockIdx.x, tid = threadIdx.x;
  float p = h1[(size_t)b*512 + tid]*w2[tid] + h1[(size_t)b*512 + 256 + tid]*w2[256 + tid];
  red[tid] = p; __syncthreads();
  for (int s2=128; s2; s2>>=1){ if (tid < s2) red[tid] += red[tid+s2]; __syncthreads(); }
  if (tid == 0) out[b] = 1.0f/(1.0f + __expf(-(red[0] + b2[0])));
}

extern "C" void kernel_launch(void* const* d_in, const int* in_sizes, int n_in,
                              void* d_out, int out_size, void* d_ws, size_t ws_size,
                              hipStream_t stream){
  const int*   x     = (const int*)d_in[0];
  const float* embed = (const float*)d_in[1];
  const float* Wihf  = (const float*)d_in[2];
  const float* Whhf  = (const float*)d_in[3];
  const float* bihf  = (const float*)d_in[4];
  const float* bhhf  = (const float*)d_in[5];
  const float* Wihb  = (const float*)d_in[6];
  const float* Whhb  = (const float*)d_in[7];
  const float* bihb  = (const float*)d_in[8];
  const float* bhhb  = (const float*)d_in[9];
  const float* fc1w  = (const float*)d_in[10];
  const float* fc1b  = (const float*)d_in[11];
  const float* fc2w  = (const float*)d_in[12];
  const float* fc2b  = (const float*)d_in[13];
  float* out = (float*)d_out;

  char* ws = (char*)d_ws;
  // layout (bytes), with lifetime aliasing:
  //   [0, 100663296)            xgq packed bf16 (dead after k_gru)
  //     alias [0, 33554432)       o2t bf16 [128][512][256]     (k_tr ..k_o5)
  //     alias [33554432, 67108864) scores f32 [128][256][256]  (k_scores..k_softmax)
  //     alias [67108864, 83886080) P bf16 [128][256][256]      (k_softmax..k_o5)
  //     alias [83886080, 84934656) psum f32 [128][4][512]      (k_o5..k_poolc)
  //     alias [84934656, 85983232) pmax f32 [128][4][512]      (k_o5..k_poolc)
  //   [100663296, 121634816)    E bf16 [32768][320]  (dead after k_xgm)
  //   [121634816, 155189248)    o2b bf16 [128][256][512]
  //   [155189248, 156172288)    W16 bf16 [1536][320]
  //   [156172288, 156958720)    Wpk
  //   [156958720, 157483008)    feats
  //   [157483008, 158007296)    Z
  //   [158007296, 158138368)    h1
  char*   xgq    = ws;
  ushort* o2t    = (ushort*)ws;
  float*  scores = (float*)(ws + 33554432);
  ushort* P      = (ushort*)(ws + 67108864);
  float*  psum   = (float*)(ws + 83886080);
  float*  pmax   = (float*)(ws + 84934656);
  ushort* E      = (ushort*)(ws + 100663296);
  ushort* o2b    = (ushort*)(ws + 121634816);
  ushort* W16    = (ushort*)(ws + 155189248);
  ushort* Wpk    = (ushort*)(ws + 156172288);
  float*  feats  = (float*)(ws + 156958720);
  float*  Z      = (float*)(ws + 157483008);
  float*  h1     = (float*)(ws + 158007296);

  k_emb<<<8192, 320, 0, stream>>>(x, embed, E);
  k_wih<<<384, 320, 0, stream>>>(Wihf, Wihb, W16);
  k_wpk<<<192, 256, 0, stream>>>(Whhf, Whhb, Wpk);
  k_xgm<<<dim3(256, 6), 256, 0, stream>>>(E, W16, bihf, bihb, bhhf, bhhb, xgq);
  k_gru<<<64, 1024, 0, stream>>>(xgq, Wpk, bhhf, bhhb, o2b);
  k_tr<<<dim3(4, 8, 128), 256, 0, stream>>>(o2b, o2t);
  k_scores<<<dim3(4, 4, 128), 256, 0, stream>>>(o2b, scores);
  k_softmax<<<8192, 256, 0, stream>>>(scores, P);
  k_o5<<<dim3(4, 8, 128), 256, 0, stream>>>(P, o2t, psum, pmax);
  k_poolc<<<256, 256, 0, stream>>>(psum, pmax, feats);
  k_z<<<512, 256, 0, stream>>>(feats, Z);
  k_fc1<<<8, 256, 0, stream>>>(Z, fc1w, fc1b, h1);
  k_fc2<<<64, 256, 0, stream>>>(h1, fc2w, fc2b, out);
}

// Round 15
// 551.657 us; speedup vs baseline: 1.0735x; 1.0735x over previous
//
#include <hip/hip_runtime.h>
#include <hip/hip_bf16.h>

typedef __hip_bfloat16 bf16;
typedef __bf16 bf16x8 __attribute__((ext_vector_type(8)));
typedef float f32x4 __attribute__((ext_vector_type(4)));

#define SEQ 256
#define NB  64
#define NV  300
#define NH  256
#define G3  768
#define D2  512
#define LOG2E  1.44269504f
#define LOG2E2 2.88539008f

__device__ __forceinline__ ushort f2bs(float f){ __bf16 t = (__bf16)f; return *(ushort*)&t; }
__device__ __forceinline__ float u2f(uint u){ return __uint_as_float(u); }

__device__ __forceinline__ float ex2(float x){
#if __has_builtin(__builtin_amdgcn_exp2f)
  return __builtin_amdgcn_exp2f(x);
#else
  return __exp2f(x);
#endif
}
__device__ __forceinline__ float rcp_(float x){
#if __has_builtin(__builtin_amdgcn_rcpf)
  return __builtin_amdgcn_rcpf(x);
#else
  return 1.0f/x;
#endif
}

// fp32 64x64 tile helper (used by fc1)
__device__ __forceinline__ void mm16(const float (*As)[68], const float (*Bs)[68],
                                     float acc[4][4], int ty, int tx){
  #pragma unroll
  for (int kk=0;kk<16;kk++){
    const float4 a4 = *(const float4*)&As[kk][ty*4];
    const float4 b4 = *(const float4*)&Bs[kk][tx*4];
    const float ai[4] = {a4.x,a4.y,a4.z,a4.w};
    const float bj[4] = {b4.x,b4.y,b4.z,b4.w};
    #pragma unroll
    for (int i=0;i<4;i++)
      #pragma unroll
      for (int j=0;j<4;j++)
        acc[i][j] = fmaf(ai[i], bj[j], acc[i][j]);
  }
}

// === prep: gathered embedding -> bf16, K padded 300->320 ===
__global__ __launch_bounds__(320) void k_emb(const int* __restrict__ x,
                                             const float* __restrict__ embed,
                                             ushort* __restrict__ E){
  const int t = threadIdx.x;
  const int rsub = t / 80, c4 = t - rsub*80;
  const int row = blockIdx.x*4 + rsub;           // 32768 rows = s*16384 + b*256 + n
  const int s = row >> 14, b = (row >> 8) & 63, n = row & 255;
  const int token = x[(b*2 + s)*SEQ + n];
  const int k = c4*4;
  float4 v = make_float4(0,0,0,0);
  if (k < NV) v = *(const float4*)(embed + (size_t)token*NV + k);
  ushort4 o;
  o.x = f2bs(v.x); o.y = f2bs(v.y); o.z = f2bs(v.z); o.w = f2bs(v.w);
  *(ushort4*)(E + (size_t)row*320 + k) = o;
}

// === prep: W_ih (f then b) -> bf16 [1536][320] ===
__global__ __launch_bounds__(320) void k_wih(const float* __restrict__ Wf,
                                             const float* __restrict__ Wb,
                                             ushort* __restrict__ W16){
  const int t = threadIdx.x;
  const int rsub = t / 80, c4 = t - rsub*80;
  const int g = blockIdx.x*4 + rsub;             // 0..1535
  const int dir = g >= G3;
  const int gw = g - dir*G3;
  const float* __restrict__ W = dir ? Wb : Wf;
  const int k = c4*4;
  float4 v = make_float4(0,0,0,0);
  if (k < NV) v = *(const float4*)(W + (size_t)gw*NV + k);
  ushort4 o;
  o.x = f2bs(v.x); o.y = f2bs(v.y); o.z = f2bs(v.z); o.w = f2bs(v.w);
  *(ushort4*)(W16 + (size_t)g*320 + k) = o;
}

// === prep: W_hh -> bf16 MFMA B-frag layout for 16-wave k_gru, log2e-scaled ===
// idx = (((dir*16+w)*3 + tau)*8 + kf)*64 + lane
// B[k][col]: col = lane&15 -> gate g = tau*256 + w*16 + col ; k = kf*32 + (lane>>4)*8 + e
__global__ __launch_bounds__(256) void k_wpk(const float* __restrict__ Wf,
                                             const float* __restrict__ Wb,
                                             ushort* __restrict__ wpk){
  const int idx = blockIdx.x*256 + threadIdx.x;   // 49152
  const int l   = idx & 63;
  const int kf  = (idx >> 6) & 7;
  const int r2  = idx >> 9;                        // (dir*16+w)*3 + tau
  const int tau = r2 % 3;
  const int r3  = r2 / 3;
  const int w   = r3 & 15;
  const int dir = r3 >> 4;
  const int g   = tau*256 + w*16 + (l & 15);
  const int kb  = kf*32 + (l >> 4)*8;
  const float sc = (tau < 2) ? LOG2E : LOG2E2;
  const float* __restrict__ W = dir ? Wb : Wf;
  #pragma unroll
  for (int e=0;e<8;e++)
    wpk[(size_t)idx*8 + e] = f2bs(W[(size_t)g*NH + kb + e] * sc);
}

// === xg GEMM (MFMA): E[32768x320] @ W16^T -> xgq, biases folded, log2e-scaled ===
// xgq layout: [blk = chain*16 + slice16][n][r4(4)][tau(3)][u(256)] bf16
// Epilogue stages C in LDS and writes coalesced 16B runs (tau,u0 are WG-constant).
__global__ __launch_bounds__(256) void k_xgm(const ushort* __restrict__ E,
    const ushort* __restrict__ W16,
    const float* __restrict__ bihf, const float* __restrict__ bihb,
    const float* __restrict__ bhhf, const float* __restrict__ bhhb,
    char* __restrict__ xgq)
{
  __shared__ __align__(16) char SM[34816];   // loop: As[0,10240)+Bs[10240,20480); epi: Cs[128][272B]
  char* As = SM;
  char* Bs = SM + 10240;
  const int tid = threadIdx.x, w = tid >> 6, l = tid & 63, l15 = l & 15, lg = l >> 4;
  const int r0 = blockIdx.x * 128;
  const int c0 = blockIdx.y * 128;
  const int dir = (c0 >= G3);
  const int cw0 = c0 - dir*G3;
  const float* __restrict__ bih = dir ? bihb : bihf;
  const float* __restrict__ bhh = dir ? bhhb : bhhf;

  const int srow = tid >> 1, sc_ = (tid & 1)*32;
  f32x4 acc[2][8] = {};

  for (int ks = 0; ks < 10; ks++){
    const uint4 a0 = *(const uint4*)((const char*)E + (size_t)(r0+srow)*640 + ks*64 + sc_);
    const uint4 a1 = *(const uint4*)((const char*)E + (size_t)(r0+srow)*640 + ks*64 + sc_ + 16);
    const uint4 b0 = *(const uint4*)((const char*)W16 + (size_t)(c0+srow)*640 + ks*64 + sc_);
    const uint4 b1 = *(const uint4*)((const char*)W16 + (size_t)(c0+srow)*640 + ks*64 + sc_ + 16);
    __syncthreads();
    *(uint4*)&As[srow*80 + sc_] = a0;
    *(uint4*)&As[srow*80 + sc_ + 16] = a1;
    *(uint4*)&Bs[srow*80 + sc_] = b0;
    *(uint4*)&Bs[srow*80 + sc_ + 16] = b1;
    __syncthreads();
    bf16x8 am[2], bn[8];
    #pragma unroll
    for (int mm=0;mm<2;mm++) am[mm] = *(const bf16x8*)&As[(w*32 + mm*16 + l15)*80 + lg*16];
    #pragma unroll
    for (int nt=0;nt<8;nt++)  bn[nt] = *(const bf16x8*)&Bs[(nt*16 + l15)*80 + lg*16];
    #pragma unroll
    for (int mm=0;mm<2;mm++)
      #pragma unroll
      for (int nt=0;nt<8;nt++)
        acc[mm][nt] = __builtin_amdgcn_mfma_f32_16x16x32_bf16(am[mm], bn[nt], acc[mm][nt], 0,0,0);
  }

  // epilogue: bias+scale -> LDS bf16 tile [128 rows][136 u16 stride]
  __syncthreads();
  ushort* Cs = (ushort*)SM;
  #pragma unroll
  for (int nt=0;nt<8;nt++){
    const int cwb = cw0 + nt*16;
    const float sc2 = (cwb < 512) ? LOG2E : LOG2E2;
    const float bias = bih[cwb + l15] + ((cwb < 512) ? bhh[cwb + l15] : 0.0f);
    #pragma unroll
    for (int mm=0;mm<2;mm++)
      #pragma unroll
      for (int j=0;j<4;j++){
        const int row = w*32 + mm*16 + lg*4 + j;
        Cs[row*136 + nt*16 + l15] = f2bs((acc[mm][nt][j] + bias) * sc2);
      }
  }
  __syncthreads();
  // coalesced out: each output row contributes one contiguous 256B run in xgq
  const int tau = cw0 >> 8;          // constant per WG
  const int u0  = cw0 & 255;         // 0 or 128
  #pragma unroll
  for (int i=0;i<8;i++){
    const int idx = i*256 + tid;     // 0..2047
    const int row = idx >> 4, c16 = idx & 15;
    const int R = r0 + row;
    const int s_ = R >> 14, b_ = (R >> 8) & 63, n_ = R & 255;
    const int blk = (s_*2 + dir)*16 + (b_ >> 2);
    const uint4 v = *(const uint4*)&Cs[row*136 + c16*8];
    *(uint4*)(xgq + ((size_t)blk*256 + n_)*6144 + ((b_&3)*3 + tau)*512 + u0*2 + c16*16) = v;
  }
}

// === GRU recurrence: 64 WGs x 1024 threads (16 waves, 4/SIMD) — round-8 body ===
// 4 batch rows per WG at MFMA tile rows {0,4,8,12}; per-thread gate work = 1 triple.
// All weights register-resident (Wr[3][8]); LDS = h dbuf only.
#define HSTR 544
__global__ __launch_bounds__(1024, 4) void k_gru(const char* __restrict__ xgq,
      const ushort* __restrict__ wpk,
      const float* __restrict__ bhhf, const float* __restrict__ bhhb,
      ushort* __restrict__ o2b)
{
  __shared__ __align__(16) char SMEM[2*16*HSTR];   // 17408 B
  const int tid = threadIdx.x, w = tid >> 6, l = tid & 63, l15 = l & 15, lg = l >> 4;
  const int wgid = blockIdx.x;
  const int chain = wgid >> 4, sl = wgid & 15;
  const int s = chain >> 1, dir = chain & 1;
  const int sb64 = s*64 + sl*4;
  const float* __restrict__ bhh = dir ? bhhb : bhhf;
  const char* wbg = (const char*)wpk + (size_t)(dir*16 + w) * 24576;

  // all 24 weight fragments resident
  bf16x8 Wr[3][8];
  #pragma unroll
  for (int tau=0; tau<3; tau++)
    #pragma unroll
    for (int kf=0; kf<8; kf++)
      Wr[tau][kf] = *(const bf16x8*)(wbg + (size_t)((tau*8 + kf)*64 + l)*16);

  const float bn = bhh[512 + w*16 + l15] * LOG2E2;

  // zero both h buffers (tile rows !=0 mod 4 stay zero forever)
  for (int k = tid; k < 4352; k += 1024) ((float*)SMEM)[k] = 0.0f;

  const int n0 = dir ? 255 : 0;
  const int qstep = dir ? -6144 : 6144;
  const int ostep = dir ? -1024 : 1024;
  // per-thread gate-input base: row lg, unit u=w*16+l15; block [r4][tau][u]
  const char* qb = xgq + ((size_t)wgid*256 + n0)*6144 + lg*1536 + (w*16 + l15)*2;
  char* op = (char*)o2b + ((size_t)(sb64 + lg)*256 + n0)*1024 + dir*512 + (w*16 + l15)*2;

  const int aoff = l15*HSTR + lg*16;
  const int hwoff = lg*4*HSTR + (w*16 + l15)*2;
  float hpv = 0.0f;

  __syncthreads();

  #pragma unroll 1
  for (int t=0; t<SEQ; t++){
    const int cur = t & 1;
    const int hcur = cur*8704, hnxt = (cur^1)*8704;

    // gate inputs: 3 ushorts (r,z,n) at imm offsets
    const ushort q0 = *(const ushort*)(qb);
    const ushort q1 = *(const ushort*)(qb + 512);
    const ushort q2 = *(const ushort*)(qb + 1024);
    qb += qstep;

    // hg = h_t @ W_hh^T : 24 MFMA per wave (M underfilled: rows 0,4,8,12 valid)
    f32x4 C[3] = {};
    #pragma unroll
    for (int kf=0; kf<8; kf++){
      const bf16x8 a = *(const bf16x8*)&SMEM[hcur + aoff + kf*64];
      C[0] = __builtin_amdgcn_mfma_f32_16x16x32_bf16(a, Wr[0][kf], C[0], 0, 0, 0);
      C[1] = __builtin_amdgcn_mfma_f32_16x16x32_bf16(a, Wr[1][kf], C[1], 0, 0, 0);
      C[2] = __builtin_amdgcn_mfma_f32_16x16x32_bf16(a, Wr[2][kf], C[2], 0, 0, 0);
    }

    // single gate triple per thread (valid C row = j0 of lane-group lg)
    const float xr = u2f((uint)q0 << 16);
    const float xz = u2f((uint)q1 << 16);
    const float xn = u2f((uint)q2 << 16);
    const float r  = rcp_(1.0f + ex2(-(xr + C[0][0])));
    const float z  = rcp_(1.0f + ex2(-(xz + C[1][0])));
    const float e2 = ex2(xn + r*(C[2][0] + bn));
    const float nn = (e2 - 1.0f) * rcp_(e2 + 1.0f);
    const float h  = nn + z*(hpv - nn);
    hpv = h;
    const ushort hs = f2bs(h);
    *(ushort*)&SMEM[hnxt + hwoff] = hs;
    *(ushort*)op = hs;
    op += ostep;
    __syncthreads();
  }
}

// === transpose o2b -> o2t (bf16), per sb 64x64 tiles ===
__global__ __launch_bounds__(256) void k_tr(const ushort* __restrict__ o2b,
                                            ushort* __restrict__ o2t){
  __shared__ __align__(16) char Ts[64*144];
  const int t = threadIdx.x;
  const int sb = blockIdx.z;
  const int n0 = blockIdx.x*64, d0 = blockIdx.y*64;
  const char* src = (const char*)o2b + (size_t)sb*262144;
  char* dst = (char*)o2t + (size_t)sb*262144;
  const int r = t >> 3, ch = t & 7;
  #pragma unroll
  for (int p=0;p<2;p++){
    const int row = r + p*32;
    const uint4 v = *(const uint4*)(src + (size_t)(n0+row)*1024 + d0*2 + ch*16);
    *(uint4*)&Ts[row*144 + ch*16] = v;
  }
  __syncthreads();
  #pragma unroll
  for (int p=0;p<2;p++){
    const int d = r + p*32;
    uint o[4];
    #pragma unroll
    for (int i=0;i<4;i++){
      const uint lo = *(const ushort*)&Ts[(ch*8 + 2*i)*144 + d*2];
      const uint hi = *(const ushort*)&Ts[(ch*8 + 2*i + 1)*144 + d*2];
      o[i] = lo | (hi << 16);
    }
    *(uint4*)(dst + (size_t)(d0+d)*512 + n0*2 + ch*16) = *(uint4*)o;
  }
}

// === scores (MFMA): o2b @ o2b^T - dist ===
__global__ __launch_bounds__(256) void k_scores(const ushort* __restrict__ o2b,
                                                float* __restrict__ sc){
  __shared__ __align__(16) char As[64*144];
  __shared__ __align__(16) char Bs[64*144];
  const int tid = threadIdx.x, w = tid >> 6, l = tid & 63, l15 = l & 15, lg = l >> 4;
  const int sb = blockIdx.z;
  const int n0 = blockIdx.x*64, m0 = blockIdx.y*64;
  const char* ob = (const char*)o2b + (size_t)sb*262144;
  const int srow = tid >> 2, scf = (tid & 3)*16;
  f32x4 acc[4] = {};
  for (int it=0; it<8; it++){
    const int k0 = it*64;
    const uint4 a0 = *(const uint4*)(ob + (size_t)(n0+srow)*1024 + k0*2 + scf);
    const uint4 a1 = *(const uint4*)(ob + (size_t)(n0+srow)*1024 + k0*2 + scf + 64);
    const uint4 b0 = *(const uint4*)(ob + (size_t)(m0+srow)*1024 + k0*2 + scf);
    const uint4 b1 = *(const uint4*)(ob + (size_t)(m0+srow)*1024 + k0*2 + scf + 64);
    __syncthreads();
    *(uint4*)&As[srow*144 + scf] = a0;
    *(uint4*)&As[srow*144 + scf + 64] = a1;
    *(uint4*)&Bs[srow*144 + scf] = b0;
    *(uint4*)&Bs[srow*144 + scf + 64] = b1;
    __syncthreads();
    #pragma unroll
    for (int ks=0; ks<2; ks++){
      const bf16x8 a = *(const bf16x8*)&As[(w*16 + l15)*144 + ks*64 + lg*16];
      #pragma unroll
      for (int nt=0; nt<4; nt++){
        const bf16x8 b = *(const bf16x8*)&Bs[(nt*16 + l15)*144 + ks*64 + lg*16];
        acc[nt] = __builtin_amdgcn_mfma_f32_16x16x32_bf16(a, b, acc[nt], 0, 0, 0);
      }
    }
  }
  #pragma unroll
  for (int nt=0; nt<4; nt++)
    #pragma unroll
    for (int j=0; j<4; j++){
      const int n = n0 + w*16 + lg*4 + j;
      const int m = m0 + nt*16 + l15;
      const float d = (float)(n - m);
      sc[((size_t)sb*SEQ + n)*SEQ + m] = acc[nt][j] - d*d*(1.0f/0.95f);
    }
}

// === softmax rows -> P bf16 ===
__global__ __launch_bounds__(256) void k_softmax(const float* __restrict__ sc,
                                                 ushort* __restrict__ P){
  const int row = blockIdx.x*4 + (threadIdx.x >> 6);
  const int lane = threadIdx.x & 63;
  const float4 v = *(const float4*)(sc + (size_t)row*SEQ + lane*4);
  float m = fmaxf(fmaxf(v.x,v.y), fmaxf(v.z,v.w));
  #pragma unroll
  for (int off=32; off; off>>=1) m = fmaxf(m, __shfl_xor(m, off));
  float4 e;
  e.x = __expf(v.x-m); e.y = __expf(v.y-m); e.z = __expf(v.z-m); e.w = __expf(v.w-m);
  float ssum = e.x+e.y+e.z+e.w;
  #pragma unroll
  for (int off=32; off; off>>=1) ssum += __shfl_xor(ssum, off);
  const float inv = 1.0f/ssum;
  uint2 o;
  o.x = (uint)f2bs(e.x*inv) | ((uint)f2bs(e.y*inv) << 16);
  o.y = (uint)f2bs(e.z*inv) | ((uint)f2bs(e.w*inv) << 16);
  *(uint2*)((char*)P + (size_t)row*512 + lane*8) = o;
}

// === o5 (MFMA): P @ o2  (B from o2t), bf16 out ===
__global__ __launch_bounds__(256) void k_o5(const ushort* __restrict__ P,
                                            const ushort* __restrict__ o2t,
                                            ushort* __restrict__ o5b){
  __shared__ __align__(16) char As[64*144];
  __shared__ __align__(16) char Bs[64*144];
  const int tid = threadIdx.x, w = tid >> 6, l = tid & 63, l15 = l & 15, lg = l >> 4;
  const int sb = blockIdx.z;
  const int n0 = blockIdx.x*64, d0 = blockIdx.y*64;
  const char* pa = (const char*)P + (size_t)sb*131072;
  const char* pb = (const char*)o2t + (size_t)sb*262144;
  const int srow = tid >> 2, scf = (tid & 3)*16;
  f32x4 acc[4] = {};
  for (int it=0; it<4; it++){
    const int k0 = it*64;
    const uint4 a0 = *(const uint4*)(pa + (size_t)(n0+srow)*512 + k0*2 + scf);
    const uint4 a1 = *(const uint4*)(pa + (size_t)(n0+srow)*512 + k0*2 + scf + 64);
    const uint4 b0 = *(const uint4*)(pb + (size_t)(d0+srow)*512 + k0*2 + scf);
    const uint4 b1 = *(const uint4*)(pb + (size_t)(d0+srow)*512 + k0*2 + scf + 64);
    __syncthreads();
    *(uint4*)&As[srow*144 + scf] = a0;
    *(uint4*)&As[srow*144 + scf + 64] = a1;
    *(uint4*)&Bs[srow*144 + scf] = b0;
    *(uint4*)&Bs[srow*144 + scf + 64] = b1;
    __syncthreads();
    #pragma unroll
    for (int ks=0; ks<2; ks++){
      const bf16x8 a = *(const bf16x8*)&As[(w*16 + l15)*144 + ks*64 + lg*16];
      #pragma unroll
      for (int nt=0; nt<4; nt++){
        const bf16x8 b = *(const bf16x8*)&Bs[(nt*16 + l15)*144 + ks*64 + lg*16];
        acc[nt] = __builtin_amdgcn_mfma_f32_16x16x32_bf16(a, b, acc[nt], 0, 0, 0);
      }
    }
  }
  #pragma unroll
  for (int nt=0; nt<4; nt++)
    #pragma unroll
    for (int j=0; j<4; j++){
      const int n = n0 + w*16 + lg*4 + j;
      const int d = d0 + nt*16 + l15;
      *(ushort*)((char*)o5b + (size_t)sb*262144 + (size_t)n*1024 + d*2) = f2bs(acc[nt][j]);
    }
}

// === mean/max pool (bf16 in) ===
__global__ __launch_bounds__(256) void k_pool(const ushort* __restrict__ o5b,
                                              float* __restrict__ feats){
  const int idx = blockIdx.x*256 + threadIdx.x;
  const int sb = idx >> 9, d = idx & 511;
  const ushort* __restrict__ Pp = o5b + (size_t)sb*SEQ*D2 + d;
  float sum = 0.0f, mx = -1e30f;
  for (int n=0;n<SEQ;n++){
    const float v = u2f(((uint)Pp[(size_t)n*D2]) << 16);
    sum += v; mx = fmaxf(mx, v);
  }
  feats[(size_t)sb*1024 + d] = sum*(1.0f/256.0f);
  feats[(size_t)sb*1024 + 512 + d] = mx;
}

__global__ __launch_bounds__(256) void k_z(const float* __restrict__ feats,
                                           float* __restrict__ Z){
  const int idx = blockIdx.x*256 + threadIdx.x;
  const int b = idx >> 11, k = idx & 2047;
  const int j = (k < 1024) ? k : (k - 1024);
  const float fa = feats[(size_t)b*1024 + j];
  const float fb = feats[(size_t)(64 + b)*1024 + j];
  Z[idx] = (k < 1024) ? fabsf(fa - fb) : fa*fb;
}

__global__ __launch_bounds__(256) void k_fc1(const float* __restrict__ Z,
                                             const float* __restrict__ w,
                                             const float* __restrict__ bias,
                                             float* __restrict__ h1){
  __shared__ float As[16][68];
  __shared__ float Bs[16][68];
  const int tid = threadIdx.x;
  const int c0 = blockIdx.x*64;
  const int lr = tid >> 2, lk = (tid & 3)*4;
  const int ty = tid >> 4, tx = tid & 15;
  float acc[4][4] = {};
  for (int k0=0;k0<2048;k0+=16){
    const float4 a = *(const float4*)(Z + (size_t)lr*2048 + k0 + lk);
    const float4 b = *(const float4*)(w + (size_t)(c0+lr)*2048 + k0 + lk);
    __syncthreads();
    As[lk+0][lr]=a.x; As[lk+1][lr]=a.y; As[lk+2][lr]=a.z; As[lk+3][lr]=a.w;
    Bs[lk+0][lr]=b.x; Bs[lk+1][lr]=b.y; Bs[lk+2][lr]=b.z; Bs[lk+3][lr]=b.w;
    __syncthreads();
    mm16(As, Bs, acc, ty, tx);
  }
  #pragma unroll
  for (int i=0;i<4;i++)
    #pragma unroll
    for (int j=0;j<4;j++)
      h1[(size_t)(ty*4+i)*512 + c0+tx*4+j] = fmaxf(acc[i][j] + bias[c0+tx*4+j], 0.0f);
}

__global__ __launch_bounds__(256) void k_fc2(const float* __restrict__ h1,
                                             const float* __restrict__ w2,
                                             const float* __restrict__ b2,
                                             float* __restrict__ out){
  __shared__ float red[256];
  const int b = blockIdx.x, tid = threadIdx.x;
  float p = h1[(size_t)b*512 + tid]*w2[tid] + h1[(size_t)b*512 + 256 + tid]*w2[256 + tid];
  red[tid] = p; __syncthreads();
  for (int s2=128; s2; s2>>=1){ if (tid < s2) red[tid] += red[tid+s2]; __syncthreads(); }
  if (tid == 0) out[b] = 1.0f/(1.0f + __expf(-(red[0] + b2[0])));
}

extern "C" void kernel_launch(void* const* d_in, const int* in_sizes, int n_in,
                              void* d_out, int out_size, void* d_ws, size_t ws_size,
                              hipStream_t stream){
  const int*   x     = (const int*)d_in[0];
  const float* embed = (const float*)d_in[1];
  const float* Wihf  = (const float*)d_in[2];
  const float* Whhf  = (const float*)d_in[3];
  const float* bihf  = (const float*)d_in[4];
  const float* bhhf  = (const float*)d_in[5];
  const float* Wihb  = (const float*)d_in[6];
  const float* Whhb  = (const float*)d_in[7];
  const float* bihb  = (const float*)d_in[8];
  const float* bhhb  = (const float*)d_in[9];
  const float* fc1w  = (const float*)d_in[10];
  const float* fc1b  = (const float*)d_in[11];
  const float* fc2w  = (const float*)d_in[12];
  const float* fc2b  = (const float*)d_in[13];
  float* out = (float*)d_out;

  char* ws = (char*)d_ws;
  // layout (bytes), with lifetime aliasing:
  //   [0, 100663296)            xgq packed bf16 (dead after k_gru)
  //     alias [0, 33554432)       o2t bf16 [128][512][256]     (k_tr ..k_o5)
  //     alias [33554432, 67108864) scores f32 [128][256][256]  (k_scores..k_softmax)
  //     alias [67108864, 83886080) P bf16 [128][256][256]      (k_softmax..k_o5)
  //     alias [83886080,117440512) o5 bf16 [128][256][512]     (k_o5..k_pool)
  //   [100663296, 121634816)    E bf16 [32768][320]  (dead after k_xgm)
  //   [121634816, 155189248)    o2b bf16 [128][256][512]
  //   [155189248, 156172288)    W16 bf16 [1536][320]
  //   [156172288, 156958720)    Wpk
  //   [156958720, 157483008)    feats
  //   [157483008, 158007296)    Z
  //   [158007296, 158138368)    h1
  char*   xgq    = ws;
  ushort* o2t    = (ushort*)ws;
  float*  scores = (float*)(ws + 33554432);
  ushort* P      = (ushort*)(ws + 67108864);
  ushort* o5b    = (ushort*)(ws + 83886080);
  ushort* E      = (ushort*)(ws + 100663296);
  ushort* o2b    = (ushort*)(ws + 121634816);
  ushort* W16    = (ushort*)(ws + 155189248);
  ushort* Wpk    = (ushort*)(ws + 156172288);
  float*  feats  = (float*)(ws + 156958720);
  float*  Z      = (float*)(ws + 157483008);
  float*  h1     = (float*)(ws + 158007296);

  k_emb<<<8192, 320, 0, stream>>>(x, embed, E);
  k_wih<<<384, 320, 0, stream>>>(Wihf, Wihb, W16);
  k_wpk<<<192, 256, 0, stream>>>(Whhf, Whhb, Wpk);
  k_xgm<<<dim3(256, 12), 256, 0, stream>>>(E, W16, bihf, bihb, bhhf, bhhb, xgq);
  k_gru<<<64, 1024, 0, stream>>>(xgq, Wpk, bhhf, bhhb, o2b);
  k_tr<<<dim3(4, 8, 128), 256, 0, stream>>>(o2b, o2t);
  k_scores<<<dim3(4, 4, 128), 256, 0, stream>>>(o2b, scores);
  k_softmax<<<8192, 256, 0, stream>>>(scores, P);
  k_o5<<<dim3(4, 8, 128), 256, 0, stream>>>(P, o2t, o5b);
  k_pool<<<256, 256, 0, stream>>>(o5b, feats);
  k_z<<<512, 256, 0, stream>>>(feats, Z);
  k_fc1<<<8, 256, 0, stream>>>(Z, fc1w, fc1b, h1);
  k_fc2<<<64, 256, 0, stream>>>(h1, fc2w, fc2b, out);
}